// Round 1
// baseline (1460.231 us; speedup 1.0000x reference)
//
#include <hip/hip_runtime.h>
#include <math.h>

#define NN 50000
#define NE 800000
#define HD 128
#define FD 16
#define NPATH 16
#define PL 8
#define NM 6
#define NS 320
#define NEGV -1000000000.0f

__device__ __forceinline__ float sigm(float x){ return 1.0f/(1.0f+expf(-x)); }

// ---- degree histogram ----
__global__ void k_deg(const int* __restrict__ ei, int* __restrict__ deg){
    int e = blockIdx.x*256 + threadIdx.x;
    if (e >= NE) return;
    atomicAdd(&deg[ei[NE + e]], 1);
}

// ---- exclusive scan over degrees (single block) ----
__global__ void k_scan(const int* __restrict__ deg, int* __restrict__ offs, int* __restrict__ cursor){
    __shared__ int buf[1024];
    __shared__ int carry;
    int tid = threadIdx.x;
    if (tid==0) carry = 0;
    __syncthreads();
    for (int base=0; base<NN; base+=1024){
        int idx = base+tid;
        int v = (idx<NN) ? deg[idx] : 0;
        buf[tid]=v; __syncthreads();
        for (int off=1; off<1024; off<<=1){
            int t = (tid>=off) ? buf[tid-off] : 0;
            __syncthreads();
            buf[tid]+=t;
            __syncthreads();
        }
        int excl = buf[tid]-v;
        if (idx<NN){ int o = carry+excl; offs[idx]=o; cursor[idx]=o; }
        __syncthreads();
        if (tid==1023) carry += buf[1023];
        __syncthreads();
    }
    if (tid==0) offs[NN]=carry;
}

// ---- fill CSR with edge ids ----
__global__ void k_fill(const int* __restrict__ ei, int* __restrict__ cursor, int* __restrict__ csr){
    int e = blockIdx.x*256 + threadIdx.x;
    if (e >= NE) return;
    int dst = ei[NE+e];
    int pos = atomicAdd(&cursor[dst], 1);
    csr[pos] = e;
}

// ---- per-node edge_feat sum; convert csr eid -> src ----
__global__ void k_ef(const int* __restrict__ ei, const float* __restrict__ edge_feat,
                     const int* __restrict__ offs, int* __restrict__ csr, float* __restrict__ ef_sum){
    int node = blockIdx.x*16 + (threadIdx.x>>4);
    int k = threadIdx.x & 15;
    if (node >= NN) return;
    int b = offs[node], e2 = offs[node+1];
    float acc = 0.f;
    for (int i=b;i<e2;i++){
        int eid = csr[i];
        acc += edge_feat[(size_t)eid*FD + k];
        if (k==0) csr[i] = ei[eid];   // same-wave lanes all read eid before this store
    }
    ef_sum[node*FD + k] = acc;
}

// ---- small weight folds: Wf = W_ep @ W_e ; bf = b_ep @ W_e + b_msg ----
__global__ void k_folds(const float* __restrict__ W_ep, const float* __restrict__ b_ep,
                        const float* __restrict__ W_msg, const float* __restrict__ b_msg,
                        float* __restrict__ Wf, float* __restrict__ bf){
    int tid = threadIdx.x;
    for (int o=tid; o<FD*HD; o+=256){
        int k=o/HD, c=o%HD;
        float acc=0.f;
        for (int m=0;m<HD;m++) acc += W_ep[k*HD+m]*W_msg[(HD+m)*HD+c];
        Wf[o]=acc;
    }
    for (int c=tid; c<HD; c+=256){
        float acc=b_msg[c];
        for (int m=0;m<HD;m++) acc += b_ep[m]*W_msg[(HD+m)*HD+c];
        bf[c]=acc;
    }
}

// ---- transpose W_ih, W_hh to [K][384] ----
__global__ void k_transpose(const float* __restrict__ Wih, const float* __restrict__ Whh,
                            float* __restrict__ WihT, float* __restrict__ WhhT){
    int o = blockIdx.x*256 + threadIdx.x;
    if (o >= HD*3*HD) return;
    int k = o/(3*HD), j = o%(3*HD);
    WihT[o] = Wih[j*HD+k];
    WhhT[o] = Whh[j*HD+k];
}

// ---- agg_e = ef_sum @ Wf + deg * bf ----
__global__ void k_agge(const float* __restrict__ ef_sum, const int* __restrict__ deg,
                       const float* __restrict__ Wf, const float* __restrict__ bf,
                       float* __restrict__ agg_e){
    int o = blockIdx.x*256 + threadIdx.x;
    int n = o/HD, c = o%HD;
    const float* es = ef_sum + n*FD;
    float acc = (float)deg[n]*bf[c];
    #pragma unroll
    for (int k=0;k<FD;k++) acc += es[k]*Wf[k*HD+c];
    agg_e[o]=acc;
}

// ---- h0 = node_feat @ W_np + b_np ----
__global__ void k_h0(const float* __restrict__ nf, const float* __restrict__ W_np,
                     const float* __restrict__ b_np, float* __restrict__ h){
    int o = blockIdx.x*256 + threadIdx.x;
    int n = o/HD, c = o%HD;
    const float* x = nf + n*FD;
    float acc = b_np[c];
    #pragma unroll
    for (int k=0;k<FD;k++) acc += x[k]*W_np[k*HD+c];
    h[o]=acc;
}

// ---- ht = h @ W_h  (W_h = first 128 rows of W_msg), tiled 64x64, K=128 in 2 chunks ----
__global__ __launch_bounds__(256) void k_ht(const float* __restrict__ h,
                                            const float* __restrict__ Wmsg,
                                            float* __restrict__ ht){
    __shared__ float As[64][68];
    __shared__ float Bs[64][64];
    int n0 = blockIdx.x*64;
    int cb = blockIdx.y*64;
    int tid = threadIdx.x;
    int tx = tid&15, ty = tid>>4;
    float acc[4][4]={};
    for (int kk=0;kk<2;kk++){
        int k0 = kk*64;
        __syncthreads();
        #pragma unroll
        for (int i=0;i<4;i++){
            int fi = tid + i*256;       // 0..1023
            int row = fi>>4;            // 16 float4 per row
            int kq = fi&15;
            int n = n0+row;
            float4 v = make_float4(0.f,0.f,0.f,0.f);
            if (n<NN) v = *(const float4*)(h + (size_t)n*HD + k0 + kq*4);
            As[kq*4+0][row]=v.x; As[kq*4+1][row]=v.y; As[kq*4+2][row]=v.z; As[kq*4+3][row]=v.w;
        }
        #pragma unroll
        for (int i=0;i<4;i++){
            int fi = tid + i*256;
            int k = fi>>4; int cq = fi&15;
            *(float4*)&Bs[k][cq*4] = *(const float4*)(Wmsg + (size_t)(k0+k)*HD + cb + cq*4);
        }
        __syncthreads();
        #pragma unroll
        for (int k=0;k<64;k++){
            float4 a = *(const float4*)&As[k][ty*4];
            float4 b = *(const float4*)&Bs[k][tx*4];
            acc[0][0]+=a.x*b.x; acc[0][1]+=a.x*b.y; acc[0][2]+=a.x*b.z; acc[0][3]+=a.x*b.w;
            acc[1][0]+=a.y*b.x; acc[1][1]+=a.y*b.y; acc[1][2]+=a.y*b.z; acc[1][3]+=a.y*b.w;
            acc[2][0]+=a.z*b.x; acc[2][1]+=a.z*b.y; acc[2][2]+=a.z*b.z; acc[2][3]+=a.z*b.w;
            acc[3][0]+=a.w*b.x; acc[3][1]+=a.w*b.y; acc[3][2]+=a.w*b.z; acc[3][3]+=a.w*b.w;
        }
    }
    int r0=ty*4, c0=tx*4;
    #pragma unroll
    for (int r=0;r<4;r++){
        int n = n0+r0+r;
        if (n<NN)
            *(float4*)(ht + (size_t)n*HD + cb + c0) = make_float4(acc[r][0],acc[r][1],acc[r][2],acc[r][3]);
    }
}

// ---- agg[n] = agg_e[n] + sum over in-edges of ht[src] ----
__global__ void k_gather(const float* __restrict__ ht, const float* __restrict__ agg_e,
                         const int* __restrict__ offs, const int* __restrict__ csr,
                         float* __restrict__ agg){
    int node = blockIdx.x*2 + (threadIdx.x>>7);
    int c = threadIdx.x & 127;
    int b = offs[node], e2 = offs[node+1];
    float acc = agg_e[(size_t)node*HD + c];
    for (int i=b;i<e2;i++){
        int s = csr[i];
        acc += ht[(size_t)s*HD + c];
    }
    agg[(size_t)node*HD + c] = acc;
}

// ---- fused: gi = agg@W_ih^T + b_ih, gh = h@W_hh^T + b_hh, GRU update -> hnew ----
__global__ __launch_bounds__(256) void k_gru(const float* __restrict__ agg, const float* __restrict__ h,
                                             const float* __restrict__ WihT, const float* __restrict__ WhhT,
                                             const float* __restrict__ b_ih, const float* __restrict__ b_hh,
                                             float* __restrict__ hnew){
    __shared__ float Ag[32][68];
    __shared__ float Ah[32][68];
    __shared__ float Bi[32][96];
    __shared__ float Bh[32][96];
    int n0 = blockIdx.x*64;
    int jb = blockIdx.y;            // 0..3 (32 j-cols each)
    int tid = threadIdx.x;
    int tx = tid&15, ty = tid>>4;
    float ai[3][4][2]={};
    float av[3][4][2]={};
    for (int kk=0;kk<4;kk++){
        int k0 = kk*32;
        __syncthreads();
        #pragma unroll
        for (int i=0;i<2;i++){
            int fi = tid + i*256;   // 0..511
            int row = fi>>3;        // 8 float4 per row
            int kq = fi&7;
            int n = n0+row;
            float4 va = make_float4(0.f,0.f,0.f,0.f), vh = va;
            if (n<NN){
                va = *(const float4*)(agg + (size_t)n*HD + k0 + kq*4);
                vh = *(const float4*)(h   + (size_t)n*HD + k0 + kq*4);
            }
            Ag[kq*4+0][row]=va.x; Ag[kq*4+1][row]=va.y; Ag[kq*4+2][row]=va.z; Ag[kq*4+3][row]=va.w;
            Ah[kq*4+0][row]=vh.x; Ah[kq*4+1][row]=vh.y; Ah[kq*4+2][row]=vh.z; Ah[kq*4+3][row]=vh.w;
        }
        #pragma unroll
        for (int i=0;i<3;i++){
            int fi = tid + i*256;   // 0..767
            int k = fi/24; int cq = fi%24;
            int g = cq>>3; int j4 = cq&7;
            int col = g*HD + jb*32 + j4*4;
            *(float4*)&Bi[k][g*32+j4*4] = *(const float4*)(WihT + (size_t)(k0+k)*(3*HD) + col);
            *(float4*)&Bh[k][g*32+j4*4] = *(const float4*)(WhhT + (size_t)(k0+k)*(3*HD) + col);
        }
        __syncthreads();
        #pragma unroll
        for (int k=0;k<32;k++){
            float4 ag4 = *(const float4*)&Ag[k][ty*4];
            float4 ah4 = *(const float4*)&Ah[k][ty*4];
            float ar[4] = {ag4.x,ag4.y,ag4.z,ag4.w};
            float hr[4] = {ah4.x,ah4.y,ah4.z,ah4.w};
            #pragma unroll
            for (int g=0; g<3; g++){
                float2 bi2 = *(const float2*)&Bi[k][g*32+tx*2];
                float2 bh2 = *(const float2*)&Bh[k][g*32+tx*2];
                #pragma unroll
                for (int r=0;r<4;r++){
                    ai[g][r][0] += ar[r]*bi2.x;
                    ai[g][r][1] += ar[r]*bi2.y;
                    av[g][r][0] += hr[r]*bh2.x;
                    av[g][r][1] += hr[r]*bh2.y;
                }
            }
        }
    }
    int jbase = jb*32 + tx*2;
    float bi_r[2] = {b_ih[jbase], b_ih[jbase+1]};
    float bi_z[2] = {b_ih[HD+jbase], b_ih[HD+jbase+1]};
    float bi_n[2] = {b_ih[2*HD+jbase], b_ih[2*HD+jbase+1]};
    float bh_r[2] = {b_hh[jbase], b_hh[jbase+1]};
    float bh_z[2] = {b_hh[HD+jbase], b_hh[HD+jbase+1]};
    float bh_n[2] = {b_hh[2*HD+jbase], b_hh[2*HD+jbase+1]};
    #pragma unroll
    for (int r=0;r<4;r++){
        int n = n0 + ty*4 + r;
        if (n >= NN) continue;
        #pragma unroll
        for (int jj=0;jj<2;jj++){
            int j = jbase + jj;
            float gr = ai[0][r][jj] + bi_r[jj] + av[0][r][jj] + bh_r[jj];
            float gz = ai[1][r][jj] + bi_z[jj] + av[1][r][jj] + bh_z[jj];
            float gin = ai[2][r][jj] + bi_n[jj];
            float ghn = av[2][r][jj] + bh_n[jj];
            float rr = sigm(gr);
            float zz = sigm(gz);
            float nn = tanhf(gin + rr*ghn);
            float hold = h[(size_t)n*HD + j];
            hnew[(size_t)n*HD + j] = (1.f-zz)*nn + zz*hold;
        }
    }
}

// ---- column sums of final h ----
__global__ void k_sum(const float* __restrict__ h, float* __restrict__ gsum){
    int c = threadIdx.x & 127;
    int rs = blockIdx.x*2 + (threadIdx.x>>7);
    float acc = 0.f;
    for (int n=rs; n<NN; n+=512)
        acc += h[(size_t)n*HD + c];
    atomicAdd(&gsum[c], acc);
}

// ---- all the tiny agents + value head ----
__global__ void k_small(const float* __restrict__ ef, const int* __restrict__ paths,
                        const int* __restrict__ pmask, const float* __restrict__ pfeat,
                        const int* __restrict__ mmask, const int* __restrict__ smask,
                        const float* __restrict__ pspec,
                        const float* __restrict__ W_ep, const float* __restrict__ b_ep,
                        const float* __restrict__ W_path, const float* __restrict__ b_path,
                        const float* __restrict__ W_mod, const float* __restrict__ b_mod,
                        const float* __restrict__ c1w, const float* __restrict__ c1b,
                        const float* __restrict__ c2w, const float* __restrict__ c2b,
                        const float* __restrict__ W_val, const float* __restrict__ b_val,
                        const float* __restrict__ gsum, float* __restrict__ out){
    __shared__ float z[NPATH][HD];
    __shared__ float lp[NPATH];
    __shared__ float lm[NM];
    __shared__ float lf[NS];
    __shared__ float spec[NS];
    __shared__ int   sel[2];
    __shared__ float scal[2];
    int tid = threadIdx.x;
    int pr = tid>>7;        // 0..3
    int c  = tid&127;
    for (int pb=0; pb<4; pb++){
        int p = pb*4 + pr;
        float acc = 0.f;
        for (int l=0;l<PL;l++){
            int eid = paths[p*PL + l];
            const float* f = ef + (size_t)eid*FD;
            #pragma unroll
            for (int k=0;k<FD;k++) acc += f[k]*W_ep[k*HD + c];
        }
        z[p][c] = acc*0.125f + b_ep[c];
    }
    __syncthreads();
    if (tid < NPATH){
        float acc = b_path[0];
        for (int k=0;k<HD;k++) acc += z[tid][k]*W_path[k];
        lp[tid] = (pmask[tid]==0) ? NEGV : acc;
    }
    __syncthreads();
    if (tid==0){
        int best=0; float bv=lp[0];
        for (int i=1;i<NPATH;i++) if (lp[i]>bv){bv=lp[i];best=i;}
        float se=0.f; for (int i=0;i<NPATH;i++) se += expf(lp[i]-bv);
        scal[0] = lp[best]-bv-logf(se);
        sel[0] = best;
    }
    __syncthreads();
    int pstar = sel[0];
    if (tid < NM){
        float acc = b_mod[tid];
        for (int k=0;k<HD;k++) acc += z[pstar][k]*W_mod[k*NM + tid];
        for (int k=0;k<3;k++)  acc += pfeat[pstar*3+k]*W_mod[(HD+k)*NM + tid];
        lm[tid] = (mmask[pstar*NM + tid]==0) ? NEGV : acc;
    }
    __syncthreads();
    if (tid==0){
        int best=0; float bv=lm[0];
        for (int i=1;i<NM;i++) if (lm[i]>bv){bv=lm[i];best=i;}
        float se=0.f; for (int i=0;i<NM;i++) se += expf(lm[i]-bv);
        scal[1] = lm[best]-bv-logf(se);
        sel[1] = best;
    }
    __syncthreads();
    int mstar = sel[1];
    if (tid < NS) spec[tid] = pspec[pstar*NS + tid];
    __syncthreads();
    if (tid < NS){
        float acc = c2b[0];
        #pragma unroll
        for (int ch=0; ch<8; ch++){
            float a = c1b[ch];
            #pragma unroll
            for (int k=0;k<5;k++){
                int ss = tid + k - 2;
                if (ss>=0 && ss<NS) a += spec[ss]*c1w[ch*5+k];
            }
            a = fmaxf(a, 0.f);
            acc += a*c2w[ch];
        }
        lf[tid] = (smask[pstar*NM*NS + mstar*NS + tid]==0) ? NEGV : acc;
    }
    __syncthreads();
    if (tid==0){
        int best=0; float bv=lf[0];
        for (int i=1;i<NS;i++) if (lf[i]>bv){bv=lf[i];best=i;}
        float se=0.f; for (int i=0;i<NS;i++) se += expf(lf[i]-bv);
        float logp_f = lf[best]-bv-logf(se);
        float g=0.f;
        for (int k=0;k<HD;k++) g += gsum[k]*W_val[k];
        float value = g/(float)NN + b_val[0];
        out[0] = (float)pstar;
        out[1] = (float)best;
        out[2] = (float)mstar;
        out[3] = scal[0] + scal[1] + logp_f;
        out[4] = value;
    }
}

extern "C" void kernel_launch(void* const* d_in, const int* in_sizes, int n_in,
                              void* d_out, int out_size, void* d_ws, size_t ws_size,
                              hipStream_t stream) {
    (void)in_sizes; (void)n_in; (void)out_size; (void)ws_size;
    const float* node_feat     = (const float*)d_in[0];
    const float* edge_feat     = (const float*)d_in[1];
    const int*   edge_index    = (const int*)d_in[2];
    const int*   paths         = (const int*)d_in[3];
    const int*   path_mask     = (const int*)d_in[4];
    const float* path_features = (const float*)d_in[5];
    const int*   mod_masks     = (const int*)d_in[6];
    const int*   spec_masks    = (const int*)d_in[7];
    const float* path_spectrum = (const float*)d_in[8];
    const float* W_np  = (const float*)d_in[9];
    const float* b_np  = (const float*)d_in[10];
    const float* W_ep  = (const float*)d_in[11];
    const float* b_ep  = (const float*)d_in[12];
    const float* W_msg = (const float*)d_in[13];
    const float* b_msg = (const float*)d_in[14];
    const float* W_ih  = (const float*)d_in[15];
    const float* b_ih  = (const float*)d_in[16];
    const float* W_hh  = (const float*)d_in[17];
    const float* b_hh  = (const float*)d_in[18];
    const float* W_path = (const float*)d_in[19];
    const float* b_path = (const float*)d_in[20];
    const float* W_mod  = (const float*)d_in[21];
    const float* b_mod  = (const float*)d_in[22];
    const float* c1w = (const float*)d_in[23];
    const float* c1b = (const float*)d_in[24];
    const float* c2w = (const float*)d_in[25];
    const float* c2b = (const float*)d_in[26];
    const float* W_val = (const float*)d_in[27];
    const float* b_val = (const float*)d_in[28];

    char* ws = (char*)d_ws;
    size_t off = 0;
    auto alloc = [&](size_t bytes)->char*{
        char* p = ws + off;
        off += (bytes + 255) & ~(size_t)255;
        return p;
    };
    int*   deg    = (int*)alloc((size_t)NN*4);
    int*   offs   = (int*)alloc((size_t)(NN+1)*4);
    int*   cursor = (int*)alloc((size_t)NN*4);
    int*   csr    = (int*)alloc((size_t)NE*4);
    float* ef_sum = (float*)alloc((size_t)NN*FD*4);
    float* Wf     = (float*)alloc((size_t)FD*HD*4);
    float* bf     = (float*)alloc((size_t)HD*4);
    float* WihT   = (float*)alloc((size_t)HD*3*HD*4);
    float* WhhT   = (float*)alloc((size_t)HD*3*HD*4);
    float* agg_e  = (float*)alloc((size_t)NN*HD*4);
    float* bufA   = (float*)alloc((size_t)NN*HD*4);
    float* bufB   = (float*)alloc((size_t)NN*HD*4);
    float* agg    = (float*)alloc((size_t)NN*HD*4);
    float* gsum   = (float*)alloc((size_t)HD*4);

    hipMemsetAsync(deg, 0, (size_t)NN*4, stream);
    hipMemsetAsync(gsum, 0, (size_t)HD*4, stream);

    k_deg<<<(NE+255)/256, 256, 0, stream>>>(edge_index, deg);
    k_scan<<<1, 1024, 0, stream>>>(deg, offs, cursor);
    k_fill<<<(NE+255)/256, 256, 0, stream>>>(edge_index, cursor, csr);
    k_ef<<<(NN+15)/16, 256, 0, stream>>>(edge_index, edge_feat, offs, csr, ef_sum);
    k_folds<<<1, 256, 0, stream>>>(W_ep, b_ep, W_msg, b_msg, Wf, bf);
    k_transpose<<<(HD*3*HD+255)/256, 256, 0, stream>>>(W_ih, W_hh, WihT, WhhT);
    k_agge<<<NN*HD/256, 256, 0, stream>>>(ef_sum, deg, Wf, bf, agg_e);
    k_h0<<<NN*HD/256, 256, 0, stream>>>(node_feat, W_np, b_np, bufA);

    float* cur = bufA;
    float* other = bufB;
    for (int it=0; it<3; it++){
        k_ht<<<dim3((NN+63)/64, HD/64), 256, 0, stream>>>(cur, W_msg, other);
        k_gather<<<NN/2/128 * 128, 256, 0, stream>>>(other, agg_e, offs, csr, agg);
        k_gru<<<dim3((NN+63)/64, 4), 256, 0, stream>>>(agg, cur, WihT, WhhT, b_ih, b_hh, other);
        float* t = cur; cur = other; other = t;
    }

    k_sum<<<256, 256, 0, stream>>>(cur, gsum);
    k_small<<<1, 512, 0, stream>>>(edge_feat, paths, path_mask, path_features,
                                   mod_masks, spec_masks, path_spectrum,
                                   W_ep, b_ep, W_path, b_path, W_mod, b_mod,
                                   c1w, c1b, c2w, c2b, W_val, b_val,
                                   gsum, (float*)d_out);
}

// Round 2
// 777.845 us; speedup vs baseline: 1.8773x; 1.8773x over previous
//
#include <hip/hip_runtime.h>
#include <math.h>

#define NN 50000
#define NE 800000
#define HD 128
#define FD 16
#define NPATH 16
#define PL 8
#define NM 6
#define NS 320
#define NEGV -1000000000.0f

typedef unsigned int uint;
typedef unsigned short ushort;
typedef short bf16x8 __attribute__((ext_vector_type(8)));
typedef float f32x4 __attribute__((ext_vector_type(4)));

__device__ __forceinline__ float sigm(float x){ return 1.0f/(1.0f+expf(-x)); }

__device__ __forceinline__ ushort f2b(float f){
    union{float f; uint u;} v; v.f=f;
    uint r = v.u + 0x7FFFu + ((v.u>>16)&1u);
    return (ushort)(r>>16);
}
__device__ __forceinline__ float b2f(ushort s){
    union{uint u; float f;} v; v.u = ((uint)s)<<16; return v.f;
}

// ---- degree histogram ----
__global__ void k_deg(const int* __restrict__ ei, int* __restrict__ deg){
    int e = blockIdx.x*256 + threadIdx.x;
    if (e >= NE) return;
    atomicAdd(&deg[ei[NE + e]], 1);
}

// ---- exclusive scan over degrees (single block, wave-shfl) ----
__global__ void k_scan(const int* __restrict__ deg, int* __restrict__ offs, int* __restrict__ cursor){
    __shared__ int wsum[16];
    __shared__ int wpre[16];
    __shared__ int carry;
    int tid = threadIdx.x, lane = tid&63, wid = tid>>6;
    if (tid==0) carry = 0;
    __syncthreads();
    for (int base=0; base<NN; base+=1024){
        int idx = base+tid;
        int v = (idx<NN) ? deg[idx] : 0;
        int x = v;
        #pragma unroll
        for (int d=1; d<64; d<<=1){ int y = __shfl_up(x, d); if (lane>=d) x += y; }
        if (lane==63) wsum[wid]=x;
        __syncthreads();
        if (tid==0){
            int s=carry;
            for (int w2=0;w2<16;w2++){ int t=wsum[w2]; wpre[w2]=s; s+=t; }
            carry=s;
        }
        __syncthreads();
        if (idx<NN){ int o = wpre[wid] + x - v; offs[idx]=o; cursor[idx]=o; }
        __syncthreads();
    }
    if (tid==0) offs[NN]=carry;
}

// ---- fill CSR with edge ids ----
__global__ void k_fill(const int* __restrict__ ei, int* __restrict__ cursor, int* __restrict__ csr){
    int e = blockIdx.x*256 + threadIdx.x;
    if (e >= NE) return;
    int dst = ei[NE+e];
    int pos = atomicAdd(&cursor[dst], 1);
    csr[pos] = e;
}

// ---- per-node edge_feat sum; convert csr eid -> src ----
__global__ void k_ef(const int* __restrict__ ei, const float* __restrict__ edge_feat,
                     const int* __restrict__ offs, int* __restrict__ csr, float* __restrict__ ef_sum){
    int node = blockIdx.x*16 + (threadIdx.x>>4);
    int k = threadIdx.x & 15;
    if (node >= NN) return;
    int b = offs[node], e2 = offs[node+1];
    float acc = 0.f;
    for (int i=b;i<e2;i++){
        int eid = csr[i];
        acc += edge_feat[(size_t)eid*FD + k];
        if (k==0) csr[i] = ei[eid];   // same-wave lanes all read eid before this store
    }
    ef_sum[node*FD + k] = acc;
}

// ---- small weight folds: Wf = W_ep @ W_e ; bf = b_ep @ W_e + b_msg ----
__global__ void k_folds(const float* __restrict__ W_ep, const float* __restrict__ b_ep,
                        const float* __restrict__ W_msg, const float* __restrict__ b_msg,
                        float* __restrict__ Wf, float* __restrict__ bf){
    int tid = threadIdx.x;
    for (int o=tid; o<FD*HD; o+=256){
        int k=o/HD, c=o%HD;
        float acc=0.f;
        for (int m=0;m<HD;m++) acc += W_ep[k*HD+m]*W_msg[(HD+m)*HD+c];
        Wf[o]=acc;
    }
    for (int c=tid; c<HD; c+=256){
        float acc=b_msg[c];
        for (int m=0;m<HD;m++) acc += b_ep[m]*W_msg[(HD+m)*HD+c];
        bf[c]=acc;
    }
}

// ---- build bf16 transposed weights:
//  WbigT[512][256]: j<256: [Wih[j]|Whh[j]] ; 256..383: [Wih[j]|0] ; 384..511: [0|Whh[j-128]]
//  WhT[128][128]:   WhT[c][k] = W_msg[k][c]
__global__ void k_wprep(const float* __restrict__ W_ih, const float* __restrict__ W_hh,
                        const float* __restrict__ W_msg,
                        ushort* __restrict__ WbigT, ushort* __restrict__ WhT){
    int idx = blockIdx.x*256 + threadIdx.x;
    if (idx < 512*256){
        int j = idx>>8, k = idx&255;
        float v;
        if (k < 128){
            v = (j < 384) ? W_ih[j*HD + k] : 0.f;
        } else {
            int k2 = k-128;
            if (j < 256)       v = W_hh[j*HD + k2];
            else if (j >= 384) v = W_hh[(j-128)*HD + k2];
            else               v = 0.f;
        }
        WbigT[idx] = f2b(v);
    } else {
        int i2 = idx - 512*256;
        if (i2 < HD*HD){
            int c = i2>>7, k = i2&127;
            WhT[i2] = f2b(W_msg[k*HD + c]);
        }
    }
}

// ---- agg_e = ef_sum @ Wf + deg * bf  (fp32) ----
__global__ void k_agge(const float* __restrict__ ef_sum, const int* __restrict__ deg,
                       const float* __restrict__ Wf, const float* __restrict__ bf,
                       float* __restrict__ agg_e){
    int o = blockIdx.x*256 + threadIdx.x;
    int n = o/HD, c = o%HD;
    const float* es = ef_sum + n*FD;
    float acc = (float)deg[n]*bf[c];
    #pragma unroll
    for (int k=0;k<FD;k++) acc += es[k]*Wf[k*HD+c];
    agg_e[o]=acc;
}

// ---- h0 = node_feat @ W_np + b_np -> bf16 ----
__global__ void k_h0(const float* __restrict__ nf, const float* __restrict__ W_np,
                     const float* __restrict__ b_np, ushort* __restrict__ h){
    int idx = blockIdx.x*256 + threadIdx.x;   // NN*64, 2 cols per thread
    int n = idx>>6, c2 = idx&63;
    const float* x = nf + (size_t)n*FD;
    int j = c2*2;
    float a0 = b_np[j], a1 = b_np[j+1];
    #pragma unroll
    for (int k=0;k<FD;k++){ float xv = x[k]; a0 += xv*W_np[k*HD+j]; a1 += xv*W_np[k*HD+j+1]; }
    ((uint*)h)[idx] = (uint)f2b(a0) | (((uint)f2b(a1))<<16);
}

// ---- bf16 MFMA GEMM: C[M][ldc(part)] = A[M][K] * Bt[N][K]^T, 128x128 tile, BK=64 ----
// SPLIT: A = [A0 (k<128) | A1 (k>=128)], both [M][128] bf16.
template<int KSTEPS, bool SPLIT>
__global__ __launch_bounds__(256) void k_gemm(const ushort* __restrict__ A0,
                                              const ushort* __restrict__ A1,
                                              const ushort* __restrict__ Bt,
                                              ushort* __restrict__ C,
                                              int M, int ldc){
    __shared__ __align__(16) short As[128*64];
    __shared__ __align__(16) short Bs[128*64];
    const int tid = threadIdx.x;
    const int lane = tid & 63, w = tid>>6;
    const int wm = w>>1, wn = w&1;
    const int m0 = blockIdx.x*128, n0 = blockIdx.y*128;
    const int K = KSTEPS*64;
    f32x4 acc[4][4] = {};
    for (int kk=0; kk<KSTEPS; ++kk){
        __syncthreads();
        #pragma unroll
        for (int i=0;i<4;i++){
            int id = tid + i*256;           // 0..1023
            int row = id>>3, s = id&7;      // row 0..127, 16B slot 0..7
            int phys = row*64 + (((s ^ (row&7)))<<3);
            // A
            int ar = m0 + row; if (ar >= M) ar = M-1;
            int kg = kk*64 + s*8;
            const ushort* srcA;
            if constexpr (SPLIT)
                srcA = (kg < 128) ? (A0 + (size_t)ar*HD + kg) : (A1 + (size_t)ar*HD + (kg-128));
            else
                srcA = A0 + (size_t)ar*HD + kg;
            *(int4*)&As[phys] = *(const int4*)srcA;
            // B
            int br = n0 + row;
            *(int4*)&Bs[phys] = *(const int4*)(Bt + (size_t)br*K + kk*64 + s*8);
        }
        __syncthreads();
        #pragma unroll
        for (int ksel=0; ksel<2; ++ksel){
            bf16x8 af[4], bfr[4];
            #pragma unroll
            for (int t=0;t<4;t++){
                int arow = wm*64 + t*16 + (lane&15);
                int aslot = (ksel*4 + (lane>>4)) ^ (arow&7);
                af[t] = *(const bf16x8*)&As[arow*64 + aslot*8];
                int brow = wn*64 + t*16 + (lane&15);
                int bslot = (ksel*4 + (lane>>4)) ^ (brow&7);
                bfr[t] = *(const bf16x8*)&Bs[brow*64 + bslot*8];
            }
            #pragma unroll
            for (int mi=0;mi<4;mi++)
                #pragma unroll
                for (int ni=0;ni<4;ni++)
                    acc[mi][ni] = __builtin_amdgcn_mfma_f32_16x16x32_bf16(af[mi], bfr[ni], acc[mi][ni], 0,0,0);
        }
    }
    #pragma unroll
    for (int mi=0;mi<4;mi++){
        #pragma unroll
        for (int r=0;r<4;r++){
            int row = m0 + wm*64 + mi*16 + (lane>>4)*4 + r;
            if (row >= M) continue;
            #pragma unroll
            for (int ni=0;ni<4;ni++){
                int col = n0 + wn*64 + ni*16 + (lane&15);
                C[(size_t)row*ldc + col] = f2b(acc[mi][ni][r]);
            }
        }
    }
}

// ---- agg[n] = bf16( agg_e[n] + sum over in-edges of ht[src] ) ----
__global__ void k_gather(const ushort* __restrict__ ht, const float* __restrict__ agg_e,
                         const int* __restrict__ offs, const int* __restrict__ csr,
                         ushort* __restrict__ agg){
    int node = blockIdx.x*4 + (threadIdx.x>>6);
    int c2 = threadIdx.x & 63;
    int b = offs[node], e2 = offs[node+1];
    float2 ae = *(const float2*)(agg_e + (size_t)node*HD + c2*2);
    float a0 = ae.x, a1 = ae.y;
    const uint* hp = (const uint*)ht;
    for (int i=b;i<e2;i++){
        int s = csr[i];
        uint v = hp[(size_t)s*64 + c2];
        a0 += b2f((ushort)(v&0xFFFF));
        a1 += b2f((ushort)(v>>16));
    }
    ((uint*)agg)[(size_t)node*64 + c2] = (uint)f2b(a0) | (((uint)f2b(a1))<<16);
}

// ---- GRU epilogue: G=[r|z|in|hn] (each 128 cols, bf16) -> hnew bf16 ----
__global__ void k_gruep(const ushort* __restrict__ G, const ushort* __restrict__ h,
                        const float* __restrict__ b_ih, const float* __restrict__ b_hh,
                        ushort* __restrict__ hnew){
    int idx = blockIdx.x*256 + threadIdx.x;   // NN*64
    int n = idx>>6, c2 = idx&63;
    const uint* g = (const uint*)G + (size_t)n*256;
    uint vr = g[c2], vz = g[64+c2], vin = g[128+c2], vhn = g[192+c2];
    uint vh = ((const uint*)h)[idx];
    int j = c2*2;
    float r0 = sigm(b2f((ushort)(vr&0xFFFF)) + b_ih[j]   + b_hh[j]);
    float r1 = sigm(b2f((ushort)(vr>>16))    + b_ih[j+1] + b_hh[j+1]);
    float z0 = sigm(b2f((ushort)(vz&0xFFFF)) + b_ih[HD+j]   + b_hh[HD+j]);
    float z1 = sigm(b2f((ushort)(vz>>16))    + b_ih[HD+j+1] + b_hh[HD+j+1]);
    float n0 = tanhf(b2f((ushort)(vin&0xFFFF)) + b_ih[2*HD+j]   + r0*(b2f((ushort)(vhn&0xFFFF)) + b_hh[2*HD+j]));
    float n1 = tanhf(b2f((ushort)(vin>>16))    + b_ih[2*HD+j+1] + r1*(b2f((ushort)(vhn>>16))    + b_hh[2*HD+j+1]));
    float h0 = (1.f-z0)*n0 + z0*b2f((ushort)(vh&0xFFFF));
    float h1 = (1.f-z1)*n1 + z1*b2f((ushort)(vh>>16));
    ((uint*)hnew)[idx] = (uint)f2b(h0) | (((uint)f2b(h1))<<16);
}

// ---- column sums of final h (bf16 in, fp32 out) ----
__global__ void k_sum(const ushort* __restrict__ h, float* __restrict__ gsum){
    int c2 = threadIdx.x & 63;
    int rs = blockIdx.x*4 + (threadIdx.x>>6);
    float a0=0.f, a1=0.f;
    const uint* hp = (const uint*)h;
    for (int n=rs; n<NN; n+=1024){
        uint v = hp[(size_t)n*64 + c2];
        a0 += b2f((ushort)(v&0xFFFF));
        a1 += b2f((ushort)(v>>16));
    }
    atomicAdd(&gsum[2*c2],   a0);
    atomicAdd(&gsum[2*c2+1], a1);
}

// ---- all the tiny agents + value head (fp32, unchanged) ----
__global__ void k_small(const float* __restrict__ ef, const int* __restrict__ paths,
                        const int* __restrict__ pmask, const float* __restrict__ pfeat,
                        const int* __restrict__ mmask, const int* __restrict__ smask,
                        const float* __restrict__ pspec,
                        const float* __restrict__ W_ep, const float* __restrict__ b_ep,
                        const float* __restrict__ W_path, const float* __restrict__ b_path,
                        const float* __restrict__ W_mod, const float* __restrict__ b_mod,
                        const float* __restrict__ c1w, const float* __restrict__ c1b,
                        const float* __restrict__ c2w, const float* __restrict__ c2b,
                        const float* __restrict__ W_val, const float* __restrict__ b_val,
                        const float* __restrict__ gsum, float* __restrict__ out){
    __shared__ float z[NPATH][HD];
    __shared__ float lp[NPATH];
    __shared__ float lm[NM];
    __shared__ float lf[NS];
    __shared__ float spec[NS];
    __shared__ int   sel[2];
    __shared__ float scal[2];
    int tid = threadIdx.x;
    int pr = tid>>7;
    int c  = tid&127;
    for (int pb=0; pb<4; pb++){
        int p = pb*4 + pr;
        float acc = 0.f;
        for (int l=0;l<PL;l++){
            int eid = paths[p*PL + l];
            const float* f = ef + (size_t)eid*FD;
            #pragma unroll
            for (int k=0;k<FD;k++) acc += f[k]*W_ep[k*HD + c];
        }
        z[p][c] = acc*0.125f + b_ep[c];
    }
    __syncthreads();
    if (tid < NPATH){
        float acc = b_path[0];
        for (int k=0;k<HD;k++) acc += z[tid][k]*W_path[k];
        lp[tid] = (pmask[tid]==0) ? NEGV : acc;
    }
    __syncthreads();
    if (tid==0){
        int best=0; float bv=lp[0];
        for (int i=1;i<NPATH;i++) if (lp[i]>bv){bv=lp[i];best=i;}
        float se=0.f; for (int i=0;i<NPATH;i++) se += expf(lp[i]-bv);
        scal[0] = lp[best]-bv-logf(se);
        sel[0] = best;
    }
    __syncthreads();
    int pstar = sel[0];
    if (tid < NM){
        float acc = b_mod[tid];
        for (int k=0;k<HD;k++) acc += z[pstar][k]*W_mod[k*NM + tid];
        for (int k=0;k<3;k++)  acc += pfeat[pstar*3+k]*W_mod[(HD+k)*NM + tid];
        lm[tid] = (mmask[pstar*NM + tid]==0) ? NEGV : acc;
    }
    __syncthreads();
    if (tid==0){
        int best=0; float bv=lm[0];
        for (int i=1;i<NM;i++) if (lm[i]>bv){bv=lm[i];best=i;}
        float se=0.f; for (int i=0;i<NM;i++) se += expf(lm[i]-bv);
        scal[1] = lm[best]-bv-logf(se);
        sel[1] = best;
    }
    __syncthreads();
    int mstar = sel[1];
    if (tid < NS) spec[tid] = pspec[pstar*NS + tid];
    __syncthreads();
    if (tid < NS){
        float acc = c2b[0];
        #pragma unroll
        for (int ch=0; ch<8; ch++){
            float a = c1b[ch];
            #pragma unroll
            for (int k=0;k<5;k++){
                int ss = tid + k - 2;
                if (ss>=0 && ss<NS) a += spec[ss]*c1w[ch*5+k];
            }
            a = fmaxf(a, 0.f);
            acc += a*c2w[ch];
        }
        lf[tid] = (smask[pstar*NM*NS + mstar*NS + tid]==0) ? NEGV : acc;
    }
    __syncthreads();
    if (tid==0){
        int best=0; float bv=lf[0];
        for (int i=1;i<NS;i++) if (lf[i]>bv){bv=lf[i];best=i;}
        float se=0.f; for (int i=0;i<NS;i++) se += expf(lf[i]-bv);
        float logp_f = lf[best]-bv-logf(se);
        float g=0.f;
        for (int k=0;k<HD;k++) g += gsum[k]*W_val[k];
        float value = g/(float)NN + b_val[0];
        out[0] = (float)pstar;
        out[1] = (float)best;
        out[2] = (float)mstar;
        out[3] = scal[0] + scal[1] + logp_f;
        out[4] = value;
    }
}

extern "C" void kernel_launch(void* const* d_in, const int* in_sizes, int n_in,
                              void* d_out, int out_size, void* d_ws, size_t ws_size,
                              hipStream_t stream) {
    (void)in_sizes; (void)n_in; (void)out_size; (void)ws_size;
    const float* node_feat     = (const float*)d_in[0];
    const float* edge_feat     = (const float*)d_in[1];
    const int*   edge_index    = (const int*)d_in[2];
    const int*   paths         = (const int*)d_in[3];
    const int*   path_mask     = (const int*)d_in[4];
    const float* path_features = (const float*)d_in[5];
    const int*   mod_masks     = (const int*)d_in[6];
    const int*   spec_masks    = (const int*)d_in[7];
    const float* path_spectrum = (const float*)d_in[8];
    const float* W_np  = (const float*)d_in[9];
    const float* b_np  = (const float*)d_in[10];
    const float* W_ep  = (const float*)d_in[11];
    const float* b_ep  = (const float*)d_in[12];
    const float* W_msg = (const float*)d_in[13];
    const float* b_msg = (const float*)d_in[14];
    const float* W_ih  = (const float*)d_in[15];
    const float* b_ih  = (const float*)d_in[16];
    const float* W_hh  = (const float*)d_in[17];
    const float* b_hh  = (const float*)d_in[18];
    const float* W_path = (const float*)d_in[19];
    const float* b_path = (const float*)d_in[20];
    const float* W_mod  = (const float*)d_in[21];
    const float* b_mod  = (const float*)d_in[22];
    const float* c1w = (const float*)d_in[23];
    const float* c1b = (const float*)d_in[24];
    const float* c2w = (const float*)d_in[25];
    const float* c2b = (const float*)d_in[26];
    const float* W_val = (const float*)d_in[27];
    const float* b_val = (const float*)d_in[28];

    char* ws = (char*)d_ws;
    size_t off = 0;
    auto alloc = [&](size_t bytes)->char*{
        char* p = ws + off;
        off += (bytes + 255) & ~(size_t)255;
        return p;
    };
    int*    deg    = (int*)alloc((size_t)NN*4);
    int*    offs   = (int*)alloc((size_t)(NN+1)*4);
    int*    cursor = (int*)alloc((size_t)NN*4);
    int*    csr    = (int*)alloc((size_t)NE*4);
    float*  ef_sum = (float*)alloc((size_t)NN*FD*4);
    float*  Wf     = (float*)alloc((size_t)FD*HD*4);
    float*  bfv    = (float*)alloc((size_t)HD*4);
    ushort* WbigT  = (ushort*)alloc((size_t)512*256*2);
    ushort* WhT    = (ushort*)alloc((size_t)HD*HD*2);
    float*  agg_e  = (float*)alloc((size_t)NN*HD*4);
    ushort* hA     = (ushort*)alloc((size_t)NN*HD*2);
    ushort* hB     = (ushort*)alloc((size_t)NN*HD*2);
    ushort* agg    = (ushort*)alloc((size_t)NN*HD*2);
    ushort* G      = (ushort*)alloc((size_t)NN*512*2);
    float*  gsum   = (float*)alloc((size_t)HD*4);
    ushort* ht     = G;   // disjoint lifetime with G: ht dies before G is written

    hipMemsetAsync(deg, 0, (size_t)NN*4, stream);
    hipMemsetAsync(gsum, 0, (size_t)HD*4, stream);

    k_deg<<<(NE+255)/256, 256, 0, stream>>>(edge_index, deg);
    k_scan<<<1, 1024, 0, stream>>>(deg, offs, cursor);
    k_fill<<<(NE+255)/256, 256, 0, stream>>>(edge_index, cursor, csr);
    k_ef<<<(NN+15)/16, 256, 0, stream>>>(edge_index, edge_feat, offs, csr, ef_sum);
    k_folds<<<1, 256, 0, stream>>>(W_ep, b_ep, W_msg, b_msg, Wf, bfv);
    k_wprep<<<(512*256 + HD*HD + 255)/256, 256, 0, stream>>>(W_ih, W_hh, W_msg, WbigT, WhT);
    k_agge<<<NN*HD/256, 256, 0, stream>>>(ef_sum, deg, Wf, bfv, agg_e);
    k_h0<<<NN*64/256, 256, 0, stream>>>(node_feat, W_np, b_np, hA);

    ushort* cur = hA;
    ushort* nxt = hB;
    const int MB = (NN+127)/128;   // 391
    for (int it=0; it<3; it++){
        k_gemm<2,false><<<dim3(MB,1), 256, 0, stream>>>(cur, (const ushort*)nullptr, WhT, ht, NN, HD);
        k_gather<<<NN/4, 256, 0, stream>>>(ht, agg_e, offs, csr, agg);
        k_gemm<4,true><<<dim3(MB,4), 256, 0, stream>>>(agg, cur, WbigT, G, NN, 512);
        k_gruep<<<NN*64/256, 256, 0, stream>>>(G, cur, b_ih, b_hh, nxt);
        ushort* t = cur; cur = nxt; nxt = t;
    }

    k_sum<<<256, 256, 0, stream>>>(cur, gsum);
    k_small<<<1, 512, 0, stream>>>(edge_feat, paths, path_mask, path_features,
                                   mod_masks, spec_masks, path_spectrum,
                                   W_ep, b_ep, W_path, b_path, W_mod, b_mod,
                                   c1w, c1b, c2w, c2b, W_val, b_val,
                                   gsum, (float*)d_out);
}

// Round 3
// 550.851 us; speedup vs baseline: 2.6509x; 1.4121x over previous
//
#include <hip/hip_runtime.h>
#include <math.h>

#define NN 50000
#define NE 800000
#define HD 128
#define FD 16
#define NPATH 16
#define PL 8
#define NM 6
#define NS 320
#define NB 196   // ceil(NN/256)
#define NEGV -1000000000.0f

typedef unsigned int uint;
typedef unsigned short ushort;
typedef short bf16x8 __attribute__((ext_vector_type(8)));
typedef float f32x4 __attribute__((ext_vector_type(4)));

__device__ __forceinline__ float sigm(float x){ return 1.0f/(1.0f+expf(-x)); }

__device__ __forceinline__ ushort f2b(float f){
    union{float f; uint u;} v; v.f=f;
    uint r = v.u + 0x7FFFu + ((v.u>>16)&1u);
    return (ushort)(r>>16);
}
__device__ __forceinline__ float b2f(ushort s){
    union{uint u; float f;} v; v.u = ((uint)s)<<16; return v.f;
}
__device__ __forceinline__ float blo(uint v){ return b2f((ushort)(v&0xFFFF)); }
__device__ __forceinline__ float bhi(uint v){ return b2f((ushort)(v>>16)); }
__device__ __forceinline__ uint pack2(float a, float b){ return (uint)f2b(a) | (((uint)f2b(b))<<16); }

// ---- degree histogram ----
__global__ void k_deg(const int* __restrict__ ei, int* __restrict__ deg){
    int e = blockIdx.x*256 + threadIdx.x;
    if (e >= NE) return;
    atomicAdd(&deg[ei[NE + e]], 1);
}

// ---- hierarchical exclusive scan: per-block local scan ----
__global__ void k_scan1(const int* __restrict__ deg, int* __restrict__ offs, int* __restrict__ bsum){
    int tid = threadIdx.x, bid = blockIdx.x;
    int idx = bid*256 + tid;
    int v = (idx<NN) ? deg[idx] : 0;
    int lane = tid&63, w = tid>>6;
    int x = v;
    #pragma unroll
    for (int d=1; d<64; d<<=1){ int y = __shfl_up(x,d); if (lane>=d) x += y; }
    __shared__ int wsum[4];
    if (lane==63) wsum[w] = x;
    __syncthreads();
    int base = 0;
    #pragma unroll
    for (int j=0;j<4;j++) if (j<w) base += wsum[j];
    if (idx<NN) offs[idx] = base + x - v;   // local exclusive
    if (tid==255) bsum[bid] = base + x;
}
// ---- scan the 196 block sums ----
__global__ void k_scan2(int* __restrict__ bsum, int* __restrict__ offs){
    int tid = threadIdx.x;
    int v = (tid<NB) ? bsum[tid] : 0;
    int lane = tid&63, w = tid>>6;
    int x = v;
    #pragma unroll
    for (int d=1; d<64; d<<=1){ int y = __shfl_up(x,d); if (lane>=d) x += y; }
    __shared__ int wsum[4];
    if (lane==63) wsum[w] = x;
    __syncthreads();
    int base = 0;
    #pragma unroll
    for (int j=0;j<4;j++) if (j<w) base += wsum[j];
    if (tid<NB) bsum[tid] = base + x - v;   // exclusive block base
    if (tid==255) offs[NN] = base + x;      // total
}
// ---- add block base, produce offs + cursor ----
__global__ void k_scan3(const int* __restrict__ bsum, int* __restrict__ offs, int* __restrict__ cursor){
    int idx = blockIdx.x*256 + threadIdx.x;
    if (idx>=NN) return;
    int o = offs[idx] + bsum[blockIdx.x];
    offs[idx]=o; cursor[idx]=o;
}

// ---- fill CSR with src node + edge id ----
__global__ void k_fill(const int* __restrict__ ei, int* __restrict__ cursor,
                       int* __restrict__ csr_src, int* __restrict__ csr_eid){
    int e = blockIdx.x*256 + threadIdx.x;
    if (e >= NE) return;
    int dst = ei[NE+e];
    int src = ei[e];
    int pos = atomicAdd(&cursor[dst], 1);
    csr_src[pos] = src;
    csr_eid[pos] = e;
}

// ---- per-node 16-wide sums of edge_feat (by eid) and node_feat (by src) ----
__global__ void k_gat16(const int* __restrict__ csr_eid, const int* __restrict__ csr_src,
                        const float* __restrict__ edge_feat, const float* __restrict__ nf,
                        const int* __restrict__ offs,
                        float* __restrict__ ef_sum, float* __restrict__ nf_sum){
    int node = blockIdx.x*4 + (threadIdx.x>>6);
    int lane = threadIdx.x & 63;
    int k = lane & 15, sub = lane >> 4;
    int b = offs[node], e2 = offs[node+1];
    float ae = 0.f, an = 0.f;
    int i = b + sub;
    for (; i + 4 < e2; i += 8){
        int e0 = csr_eid[i], e1 = csr_eid[i+4];
        int s0 = csr_src[i], s1 = csr_src[i+4];
        float f0 = edge_feat[(size_t)e0*FD + k];
        float g0 = nf[(size_t)s0*FD + k];
        float f1 = edge_feat[(size_t)e1*FD + k];
        float g1 = nf[(size_t)s1*FD + k];
        ae += f0 + f1; an += g0 + g1;
    }
    if (i < e2){
        int e0 = csr_eid[i]; int s0 = csr_src[i];
        ae += edge_feat[(size_t)e0*FD + k];
        an += nf[(size_t)s0*FD + k];
    }
    ae += __shfl_xor(ae, 16); ae += __shfl_xor(ae, 32);
    an += __shfl_xor(an, 16); an += __shfl_xor(an, 32);
    if (sub == 0){ ef_sum[node*FD + k] = ae; nf_sum[node*FD + k] = an; }
}

// ---- weight folds: Wf = W_ep@W_e ; bf = b_ep@W_e + b_msg ; Wnph = W_np@W_h ; bnph = b_np@W_h ----
__global__ void k_folds(const float* __restrict__ W_ep, const float* __restrict__ b_ep,
                        const float* __restrict__ W_msg, const float* __restrict__ b_msg,
                        const float* __restrict__ W_np, const float* __restrict__ b_np,
                        float* __restrict__ Wf, float* __restrict__ bfv,
                        float* __restrict__ Wnph, float* __restrict__ bnph){
    int o = blockIdx.x*256 + threadIdx.x;
    if (o < 2048){
        int k=o>>7, c=o&127;
        float acc=0.f;
        for (int m=0;m<HD;m++) acc += W_ep[k*HD+m]*W_msg[(HD+m)*HD+c];
        Wf[o]=acc;
    } else if (o < 4096){
        int o2=o-2048; int k=o2>>7, c=o2&127;
        float acc=0.f;
        for (int m=0;m<HD;m++) acc += W_np[k*HD+m]*W_msg[m*HD+c];
        Wnph[o2]=acc;
    } else if (o < 4224){
        int c=o-4096;
        float acc=b_msg[c];
        for (int m=0;m<HD;m++) acc += b_ep[m]*W_msg[(HD+m)*HD+c];
        bfv[c]=acc;
    } else if (o < 4352){
        int c=o-4224;
        float acc=0.f;
        for (int m=0;m<HD;m++) acc += b_np[m]*W_msg[m*HD+c];
        bnph[c]=acc;
    }
}

// ---- build bf16 transposed weights ----
__global__ void k_wprep(const float* __restrict__ W_ih, const float* __restrict__ W_hh,
                        const float* __restrict__ W_msg,
                        ushort* __restrict__ WbigT, ushort* __restrict__ WhT){
    int idx = blockIdx.x*256 + threadIdx.x;
    if (idx < 512*256){
        int j = idx>>8, k = idx&255;
        float v;
        if (k < 128){
            v = (j < 384) ? W_ih[j*HD + k] : 0.f;
        } else {
            int k2 = k-128;
            if (j < 256)       v = W_hh[j*HD + k2];
            else if (j >= 384) v = W_hh[(j-128)*HD + k2];
            else               v = 0.f;
        }
        WbigT[idx] = f2b(v);
    } else {
        int i2 = idx - 512*256;
        if (i2 < HD*HD){
            int c = i2>>7, k = i2&127;
            WhT[i2] = f2b(W_msg[k*HD + c]);
        }
    }
}

// ---- agg_e (for iters 2,3) and agg for iter 1, both bf16 ----
__global__ void k_aggboth(const float* __restrict__ ef_sum, const float* __restrict__ nf_sum,
                          const int* __restrict__ deg,
                          const float* __restrict__ Wf, const float* __restrict__ bfv,
                          const float* __restrict__ Wnph, const float* __restrict__ bnph,
                          ushort* __restrict__ agg_e, ushort* __restrict__ agg){
    int idx = blockIdx.x*256 + threadIdx.x;   // NN*64
    int n = idx>>6, c2 = idx&63;
    int j = c2*2;
    const float* es = ef_sum + n*FD;
    const float* ns = nf_sum + n*FD;
    float d = (float)deg[n];
    float e0 = d*bfv[j], e1 = d*bfv[j+1];
    #pragma unroll
    for (int k=0;k<FD;k++){ float v=es[k]; e0 += v*Wf[k*HD+j]; e1 += v*Wf[k*HD+j+1]; }
    float a0 = e0 + d*bnph[j], a1 = e1 + d*bnph[j+1];
    #pragma unroll
    for (int k=0;k<FD;k++){ float v=ns[k]; a0 += v*Wnph[k*HD+j]; a1 += v*Wnph[k*HD+j+1]; }
    ((uint*)agg_e)[idx] = pack2(e0,e1);
    ((uint*)agg)[idx]   = pack2(a0,a1);
}

// ---- h0 = node_feat @ W_np + b_np -> bf16 ----
__global__ void k_h0(const float* __restrict__ nf, const float* __restrict__ W_np,
                     const float* __restrict__ b_np, ushort* __restrict__ h){
    int idx = blockIdx.x*256 + threadIdx.x;   // NN*64
    int n = idx>>6, c2 = idx&63;
    const float* x = nf + (size_t)n*FD;
    int j = c2*2;
    float a0 = b_np[j], a1 = b_np[j+1];
    #pragma unroll
    for (int k=0;k<FD;k++){ float xv = x[k]; a0 += xv*W_np[k*HD+j]; a1 += xv*W_np[k*HD+j+1]; }
    ((uint*)h)[idx] = pack2(a0,a1);
}

// ---- bf16 MFMA GEMM: C[M][ldc] = A[M][K] * Bt[N][K]^T, 128x128 tile, BK=64 ----
template<int KSTEPS, bool SPLIT>
__global__ __launch_bounds__(256) void k_gemm(const ushort* __restrict__ A0,
                                              const ushort* __restrict__ A1,
                                              const ushort* __restrict__ Bt,
                                              ushort* __restrict__ C,
                                              int M, int ldc){
    __shared__ __align__(16) short As[128*64];
    __shared__ __align__(16) short Bs[128*64];
    const int tid = threadIdx.x;
    const int lane = tid & 63, w = tid>>6;
    const int wm = w>>1, wn = w&1;
    const int m0 = blockIdx.x*128, n0 = blockIdx.y*128;
    const int K = KSTEPS*64;
    f32x4 acc[4][4] = {};
    for (int kk=0; kk<KSTEPS; ++kk){
        __syncthreads();
        #pragma unroll
        for (int i=0;i<4;i++){
            int id = tid + i*256;           // 0..1023
            int row = id>>3, s = id&7;      // row 0..127, 16B slot 0..7
            int phys = row*64 + (((s ^ (row&7)))<<3);
            int ar = m0 + row; if (ar >= M) ar = M-1;
            int kg = kk*64 + s*8;
            const ushort* srcA;
            if constexpr (SPLIT)
                srcA = (kg < 128) ? (A0 + (size_t)ar*HD + kg) : (A1 + (size_t)ar*HD + (kg-128));
            else
                srcA = A0 + (size_t)ar*HD + kg;
            *(int4*)&As[phys] = *(const int4*)srcA;
            int br = n0 + row;
            *(int4*)&Bs[phys] = *(const int4*)(Bt + (size_t)br*K + kk*64 + s*8);
        }
        __syncthreads();
        #pragma unroll
        for (int ksel=0; ksel<2; ++ksel){
            bf16x8 af[4], bfr[4];
            #pragma unroll
            for (int t=0;t<4;t++){
                int arow = wm*64 + t*16 + (lane&15);
                int aslot = (ksel*4 + (lane>>4)) ^ (arow&7);
                af[t] = *(const bf16x8*)&As[arow*64 + aslot*8];
                int brow = wn*64 + t*16 + (lane&15);
                int bslot = (ksel*4 + (lane>>4)) ^ (brow&7);
                bfr[t] = *(const bf16x8*)&Bs[brow*64 + bslot*8];
            }
            #pragma unroll
            for (int mi=0;mi<4;mi++)
                #pragma unroll
                for (int ni=0;ni<4;ni++)
                    acc[mi][ni] = __builtin_amdgcn_mfma_f32_16x16x32_bf16(af[mi], bfr[ni], acc[mi][ni], 0,0,0);
        }
    }
    #pragma unroll
    for (int mi=0;mi<4;mi++){
        #pragma unroll
        for (int r=0;r<4;r++){
            int row = m0 + wm*64 + mi*16 + (lane>>4)*4 + r;
            if (row >= M) continue;
            #pragma unroll
            for (int ni=0;ni<4;ni++){
                int col = n0 + wn*64 + ni*16 + (lane&15);
                C[(size_t)row*ldc + col] = f2b(acc[mi][ni][r]);
            }
        }
    }
}

// ---- agg[n] = bf16( agg_e[n] + sum over in-edges of ht[src] ), 8-deep pipelined gather ----
__global__ void k_gather(const ushort* __restrict__ ht, const ushort* __restrict__ agg_e,
                         const int* __restrict__ offs, const int* __restrict__ csr_src,
                         ushort* __restrict__ agg){
    int node = blockIdx.x*4 + (threadIdx.x>>6);
    int c2 = threadIdx.x & 63;
    int b = offs[node], e2 = offs[node+1];
    uint ae = ((const uint*)agg_e)[(size_t)node*64 + c2];
    float a0 = blo(ae), a1 = bhi(ae);
    const uint* hp = (const uint*)ht;
    int i = b;
    for (; i + 8 <= e2; i += 8){
        int s0=csr_src[i],  s1=csr_src[i+1], s2=csr_src[i+2], s3=csr_src[i+3];
        int s4=csr_src[i+4],s5=csr_src[i+5], s6=csr_src[i+6], s7=csr_src[i+7];
        uint v0=hp[(size_t)s0*64+c2], v1=hp[(size_t)s1*64+c2],
             v2=hp[(size_t)s2*64+c2], v3=hp[(size_t)s3*64+c2],
             v4=hp[(size_t)s4*64+c2], v5=hp[(size_t)s5*64+c2],
             v6=hp[(size_t)s6*64+c2], v7=hp[(size_t)s7*64+c2];
        a0 += blo(v0)+blo(v1)+blo(v2)+blo(v3)+blo(v4)+blo(v5)+blo(v6)+blo(v7);
        a1 += bhi(v0)+bhi(v1)+bhi(v2)+bhi(v3)+bhi(v4)+bhi(v5)+bhi(v6)+bhi(v7);
    }
    if (i + 4 <= e2){
        int s0=csr_src[i],s1=csr_src[i+1],s2=csr_src[i+2],s3=csr_src[i+3];
        uint v0=hp[(size_t)s0*64+c2], v1=hp[(size_t)s1*64+c2],
             v2=hp[(size_t)s2*64+c2], v3=hp[(size_t)s3*64+c2];
        a0 += blo(v0)+blo(v1)+blo(v2)+blo(v3);
        a1 += bhi(v0)+bhi(v1)+bhi(v2)+bhi(v3);
        i += 4;
    }
    for (; i < e2; ++i){
        uint v = hp[(size_t)csr_src[i]*64+c2];
        a0 += blo(v); a1 += bhi(v);
    }
    ((uint*)agg)[(size_t)node*64 + c2] = pack2(a0,a1);
}

// ---- GRU epilogue ----
__global__ void k_gruep(const ushort* __restrict__ G, const ushort* __restrict__ h,
                        const float* __restrict__ b_ih, const float* __restrict__ b_hh,
                        ushort* __restrict__ hnew){
    int idx = blockIdx.x*256 + threadIdx.x;   // NN*64
    int n = idx>>6, c2 = idx&63;
    const uint* g = (const uint*)G + (size_t)n*256;
    uint vr = g[c2], vz = g[64+c2], vin = g[128+c2], vhn = g[192+c2];
    uint vh = ((const uint*)h)[idx];
    int j = c2*2;
    float r0 = sigm(blo(vr) + b_ih[j]   + b_hh[j]);
    float r1 = sigm(bhi(vr) + b_ih[j+1] + b_hh[j+1]);
    float z0 = sigm(blo(vz) + b_ih[HD+j]   + b_hh[HD+j]);
    float z1 = sigm(bhi(vz) + b_ih[HD+j+1] + b_hh[HD+j+1]);
    float n0 = tanhf(blo(vin) + b_ih[2*HD+j]   + r0*(blo(vhn) + b_hh[2*HD+j]));
    float n1 = tanhf(bhi(vin) + b_ih[2*HD+j+1] + r1*(bhi(vhn) + b_hh[2*HD+j+1]));
    float h0 = (1.f-z0)*n0 + z0*blo(vh);
    float h1 = (1.f-z1)*n1 + z1*bhi(vh);
    ((uint*)hnew)[idx] = pack2(h0,h1);
}

// ---- column sums of final h ----
__global__ void k_sum(const ushort* __restrict__ h, float* __restrict__ gsum){
    int c2 = threadIdx.x & 63;
    int rs = blockIdx.x*4 + (threadIdx.x>>6);
    float a0=0.f, a1=0.f;
    const uint* hp = (const uint*)h;
    for (int n=rs; n<NN; n+=1024){
        uint v = hp[(size_t)n*64 + c2];
        a0 += blo(v); a1 += bhi(v);
    }
    atomicAdd(&gsum[2*c2],   a0);
    atomicAdd(&gsum[2*c2+1], a1);
}

// ---- tiny agents + value head (fp32) ----
__global__ void k_small(const float* __restrict__ ef, const int* __restrict__ paths,
                        const int* __restrict__ pmask, const float* __restrict__ pfeat,
                        const int* __restrict__ mmask, const int* __restrict__ smask,
                        const float* __restrict__ pspec,
                        const float* __restrict__ W_ep, const float* __restrict__ b_ep,
                        const float* __restrict__ W_path, const float* __restrict__ b_path,
                        const float* __restrict__ W_mod, const float* __restrict__ b_mod,
                        const float* __restrict__ c1w, const float* __restrict__ c1b,
                        const float* __restrict__ c2w, const float* __restrict__ c2b,
                        const float* __restrict__ W_val, const float* __restrict__ b_val,
                        const float* __restrict__ gsum, float* __restrict__ out){
    __shared__ float z[NPATH][HD];
    __shared__ float lp[NPATH];
    __shared__ float lm[NM];
    __shared__ float lf[NS];
    __shared__ float spec[NS];
    __shared__ int   sel[2];
    __shared__ float scal[2];
    int tid = threadIdx.x;
    int pr = tid>>7;
    int c  = tid&127;
    for (int pb=0; pb<4; pb++){
        int p = pb*4 + pr;
        float acc = 0.f;
        for (int l=0;l<PL;l++){
            int eid = paths[p*PL + l];
            const float* f = ef + (size_t)eid*FD;
            #pragma unroll
            for (int k=0;k<FD;k++) acc += f[k]*W_ep[k*HD + c];
        }
        z[p][c] = acc*0.125f + b_ep[c];
    }
    __syncthreads();
    if (tid < NPATH){
        float acc = b_path[0];
        for (int k=0;k<HD;k++) acc += z[tid][k]*W_path[k];
        lp[tid] = (pmask[tid]==0) ? NEGV : acc;
    }
    __syncthreads();
    if (tid==0){
        int best=0; float bv=lp[0];
        for (int i=1;i<NPATH;i++) if (lp[i]>bv){bv=lp[i];best=i;}
        float se=0.f; for (int i=0;i<NPATH;i++) se += expf(lp[i]-bv);
        scal[0] = lp[best]-bv-logf(se);
        sel[0] = best;
    }
    __syncthreads();
    int pstar = sel[0];
    if (tid < NM){
        float acc = b_mod[tid];
        for (int k=0;k<HD;k++) acc += z[pstar][k]*W_mod[k*NM + tid];
        for (int k=0;k<3;k++)  acc += pfeat[pstar*3+k]*W_mod[(HD+k)*NM + tid];
        lm[tid] = (mmask[pstar*NM + tid]==0) ? NEGV : acc;
    }
    __syncthreads();
    if (tid==0){
        int best=0; float bv=lm[0];
        for (int i=1;i<NM;i++) if (lm[i]>bv){bv=lm[i];best=i;}
        float se=0.f; for (int i=0;i<NM;i++) se += expf(lm[i]-bv);
        scal[1] = lm[best]-bv-logf(se);
        sel[1] = best;
    }
    __syncthreads();
    int mstar = sel[1];
    if (tid < NS) spec[tid] = pspec[pstar*NS + tid];
    __syncthreads();
    if (tid < NS){
        float acc = c2b[0];
        #pragma unroll
        for (int ch=0; ch<8; ch++){
            float a = c1b[ch];
            #pragma unroll
            for (int k=0;k<5;k++){
                int ss = tid + k - 2;
                if (ss>=0 && ss<NS) a += spec[ss]*c1w[ch*5+k];
            }
            a = fmaxf(a, 0.f);
            acc += a*c2w[ch];
        }
        lf[tid] = (smask[pstar*NM*NS + mstar*NS + tid]==0) ? NEGV : acc;
    }
    __syncthreads();
    if (tid==0){
        int best=0; float bv=lf[0];
        for (int i=1;i<NS;i++) if (lf[i]>bv){bv=lf[i];best=i;}
        float se=0.f; for (int i=0;i<NS;i++) se += expf(lf[i]-bv);
        float logp_f = lf[best]-bv-logf(se);
        float g=0.f;
        for (int k=0;k<HD;k++) g += gsum[k]*W_val[k];
        float value = g/(float)NN + b_val[0];
        out[0] = (float)pstar;
        out[1] = (float)best;
        out[2] = (float)mstar;
        out[3] = scal[0] + scal[1] + logp_f;
        out[4] = value;
    }
}

extern "C" void kernel_launch(void* const* d_in, const int* in_sizes, int n_in,
                              void* d_out, int out_size, void* d_ws, size_t ws_size,
                              hipStream_t stream) {
    (void)in_sizes; (void)n_in; (void)out_size; (void)ws_size;
    const float* node_feat     = (const float*)d_in[0];
    const float* edge_feat     = (const float*)d_in[1];
    const int*   edge_index    = (const int*)d_in[2];
    const int*   paths         = (const int*)d_in[3];
    const int*   path_mask     = (const int*)d_in[4];
    const float* path_features = (const float*)d_in[5];
    const int*   mod_masks     = (const int*)d_in[6];
    const int*   spec_masks    = (const int*)d_in[7];
    const float* path_spectrum = (const float*)d_in[8];
    const float* W_np  = (const float*)d_in[9];
    const float* b_np  = (const float*)d_in[10];
    const float* W_ep  = (const float*)d_in[11];
    const float* b_ep  = (const float*)d_in[12];
    const float* W_msg = (const float*)d_in[13];
    const float* b_msg = (const float*)d_in[14];
    const float* W_ih  = (const float*)d_in[15];
    const float* b_ih  = (const float*)d_in[16];
    const float* W_hh  = (const float*)d_in[17];
    const float* b_hh  = (const float*)d_in[18];
    const float* W_path = (const float*)d_in[19];
    const float* b_path = (const float*)d_in[20];
    const float* W_mod  = (const float*)d_in[21];
    const float* b_mod  = (const float*)d_in[22];
    const float* c1w = (const float*)d_in[23];
    const float* c1b = (const float*)d_in[24];
    const float* c2w = (const float*)d_in[25];
    const float* c2b = (const float*)d_in[26];
    const float* W_val = (const float*)d_in[27];
    const float* b_val = (const float*)d_in[28];

    char* ws = (char*)d_ws;
    size_t off = 0;
    auto alloc = [&](size_t bytes)->char*{
        char* p = ws + off;
        off += (bytes + 255) & ~(size_t)255;
        return p;
    };
    int*    deg     = (int*)alloc((size_t)NN*4);
    int*    offs    = (int*)alloc((size_t)(NN+1)*4);
    int*    cursor  = (int*)alloc((size_t)NN*4);
    int*    bsum    = (int*)alloc((size_t)NB*4);
    int*    csr_src = (int*)alloc((size_t)NE*4);
    int*    csr_eid = (int*)alloc((size_t)NE*4);
    float*  ef_sum  = (float*)alloc((size_t)NN*FD*4);
    float*  nf_sum  = (float*)alloc((size_t)NN*FD*4);
    float*  Wf      = (float*)alloc((size_t)FD*HD*4);
    float*  bfv     = (float*)alloc((size_t)HD*4);
    float*  Wnph    = (float*)alloc((size_t)FD*HD*4);
    float*  bnph    = (float*)alloc((size_t)HD*4);
    ushort* WbigT   = (ushort*)alloc((size_t)512*256*2);
    ushort* WhT     = (ushort*)alloc((size_t)HD*HD*2);
    ushort* agg_e   = (ushort*)alloc((size_t)NN*HD*2);
    ushort* hA      = (ushort*)alloc((size_t)NN*HD*2);
    ushort* hB      = (ushort*)alloc((size_t)NN*HD*2);
    ushort* agg     = (ushort*)alloc((size_t)NN*HD*2);
    ushort* G       = (ushort*)alloc((size_t)NN*512*2);
    float*  gsum    = (float*)alloc((size_t)HD*4);
    ushort* ht      = G;   // disjoint lifetime with G

    hipMemsetAsync(deg, 0, (size_t)NN*4, stream);
    hipMemsetAsync(gsum, 0, (size_t)HD*4, stream);

    k_deg<<<(NE+255)/256, 256, 0, stream>>>(edge_index, deg);
    k_scan1<<<NB, 256, 0, stream>>>(deg, offs, bsum);
    k_scan2<<<1, 256, 0, stream>>>(bsum, offs);
    k_scan3<<<NB, 256, 0, stream>>>(bsum, offs, cursor);
    k_fill<<<(NE+255)/256, 256, 0, stream>>>(edge_index, cursor, csr_src, csr_eid);
    k_gat16<<<NN/4, 256, 0, stream>>>(csr_eid, csr_src, edge_feat, node_feat, offs, ef_sum, nf_sum);
    k_folds<<<17, 256, 0, stream>>>(W_ep, b_ep, W_msg, b_msg, W_np, b_np, Wf, bfv, Wnph, bnph);
    k_wprep<<<(512*256 + HD*HD + 255)/256, 256, 0, stream>>>(W_ih, W_hh, W_msg, WbigT, WhT);
    k_aggboth<<<NN*64/256, 256, 0, stream>>>(ef_sum, nf_sum, deg, Wf, bfv, Wnph, bnph, agg_e, agg);
    k_h0<<<NN*64/256, 256, 0, stream>>>(node_feat, W_np, b_np, hA);

    ushort* cur = hA;
    ushort* nxt = hB;
    const int MB = (NN+127)/128;   // 391
    for (int it=0; it<3; it++){
        if (it > 0){
            k_gemm<2,false><<<dim3(MB,1), 256, 0, stream>>>(cur, (const ushort*)nullptr, WhT, ht, NN, HD);
            k_gather<<<NN/4, 256, 0, stream>>>(ht, agg_e, offs, csr_src, agg);
        }
        k_gemm<4,true><<<dim3(MB,4), 256, 0, stream>>>(agg, cur, WbigT, G, NN, 512);
        k_gruep<<<NN*64/256, 256, 0, stream>>>(G, cur, b_ih, b_hh, nxt);
        ushort* t = cur; cur = nxt; nxt = t;
    }

    k_sum<<<256, 256, 0, stream>>>(cur, gsum);
    k_small<<<1, 512, 0, stream>>>(edge_feat, paths, path_mask, path_features,
                                   mod_masks, spec_masks, path_spectrum,
                                   W_ep, b_ep, W_path, b_path, W_mod, b_mod,
                                   c1w, c1b, c2w, c2b, W_val, b_val,
                                   gsum, (float*)d_out);
}